// Round 2
// baseline (307.995 us; speedup 1.0000x reference)
//
#include <hip/hip_runtime.h>
#include <hip/hip_bf16.h>

// Problem constants (fixed by setup_inputs): B=2, H=W=64, T=4096, C=192
#define BATCH 2
#define TLEN 4096
#define CC 192
#define NPAD 640           // Z row length: 576 cols (k|v|r) padded to 5*128
#define PADC 2

__device__ __constant__ float PRF_X[16] = {-2,-2,-2,-2, -2,-1,0,1, 2,2,2,2, -1,0,1,2};
__device__ __constant__ float PRF_Y[16] = {-2,-1,0,1, 2,2,2,2, -1,0,1,2, -2,-2,-2,-2};

// Bs swizzle: insert 4 floats every 32 -> breaks the 4-way bank collision of
// tx*32B-strided b128 reads (verified <=2-way across the wave).
#define SWZ(n) ((n) + (((n) >> 5) << 2))

// ---------------- build xx (q_shift output) ----------------
__global__ __launch_bounds__(256) void k_build_xx(const float* __restrict__ x,
                                                  float* __restrict__ XX) {
    int idx = blockIdx.x * 256 + threadIdx.x;
    if (idx >= BATCH * TLEN * CC) return;
    int tg = idx / CC;
    int t  = tg & (TLEN - 1);
    int c  = idx - tg * CC;
    int i  = t >> 6;
    int j  = t & 63;
    int g  = c / 48;
    float v;
    if (g == 0)      v = (j > 0)  ? x[idx - CC]      : 0.0f;
    else if (g == 1) v = (j < 63) ? x[idx + CC]      : 0.0f;
    else if (g == 2) v = (i > 0)  ? x[idx - 64 * CC] : 0.0f;
    else             v = (i < 63) ? x[idx + 64 * CC] : 0.0f;
    XX[idx] = v;
}

// ---------------- build concatenated, mix-scaled weights ----------------
// Wcat (384 x 640): rows 0..191 = mix[c]*W[c,:], rows 192..383 = (1-mix[c])*W[c,:]
// col blocks: [0,192)=Wk  [192,384)=Wv  [384,576)=Wr  [576,640)=zero pad
__global__ __launch_bounds__(256) void k_build_wcat(const float* __restrict__ Wk,
                                                    const float* __restrict__ Wv,
                                                    const float* __restrict__ Wr,
                                                    const float* __restrict__ mk,
                                                    const float* __restrict__ mv,
                                                    const float* __restrict__ mr,
                                                    float* __restrict__ Wcat) {
    int idx = blockIdx.x * 256 + threadIdx.x;
    if (idx >= 384 * NPAD) return;
    int r   = idx / NPAD;
    int col = idx - r * NPAD;
    if (col >= 576) { Wcat[idx] = 0.0f; return; }
    int cb = col / CC;
    int cc = col - cb * CC;
    const float* W   = (cb == 0) ? Wk : (cb == 1) ? Wv : Wr;
    const float* mix = (cb == 0) ? mk : (cb == 1) ? mv : mr;
    float v;
    if (r < CC) v = mix[r] * W[r * CC + cc];
    else        v = (1.0f - mix[r - CC]) * W[(r - CC) * CC + cc];
    Wcat[idx] = v;
}

// ---------------- GEMM1: Z = [x | xx] @ Wcat ----------------
// M=8192 N=640 K=384. BM=BN=128, BK=16, 256 threads, 8x8 micro-tile.
// Double-buffered LDS, register prefetch, one barrier per K-step.
__global__ __launch_bounds__(256) void k_gemm1(const float* __restrict__ A0,
                                               const float* __restrict__ A1,
                                               const float* __restrict__ B,
                                               float* __restrict__ Cmat) {
    __shared__ float As[2][16][132];
    __shared__ float Bs[2][16][144];
    const int tid = threadIdx.x;
    const int bm = blockIdx.y * 128;
    const int bn = blockIdx.x * 128;
    const int tx = tid & 15, ty = tid >> 4;
    const int ar  = tid >> 1;           // A-load row 0..127
    const int akh = (tid & 1) * 8;      // A-load k offset
    const int bk  = tid >> 4;           // B-load k row 0..15
    const int bn8 = (tid & 15) * 8;     // B-load col offset

    float acc[8][8] = {};
    float4 a0, a1, b0, b1;

    auto loadG = [&](int k0, float4& ra0, float4& ra1, float4& rb0, float4& rb1) {
        const float* Ab = (k0 < CC) ? A0 : A1;
        int kl = (k0 < CC) ? k0 : k0 - CC;
        const float* pa = Ab + (size_t)(bm + ar) * CC + kl + akh;
        ra0 = *(const float4*)pa;
        ra1 = *(const float4*)(pa + 4);
        const float* pb = B + (size_t)(k0 + bk) * NPAD + bn + bn8;
        rb0 = *(const float4*)pb;
        rb1 = *(const float4*)(pb + 4);
    };
    auto stage = [&](int buf, float4 ra0, float4 ra1, float4 rb0, float4 rb1) {
        As[buf][akh + 0][ar] = ra0.x; As[buf][akh + 1][ar] = ra0.y;
        As[buf][akh + 2][ar] = ra0.z; As[buf][akh + 3][ar] = ra0.w;
        As[buf][akh + 4][ar] = ra1.x; As[buf][akh + 5][ar] = ra1.y;
        As[buf][akh + 6][ar] = ra1.z; As[buf][akh + 7][ar] = ra1.w;
        *(float4*)&Bs[buf][bk][SWZ(bn8)]     = rb0;
        *(float4*)&Bs[buf][bk][SWZ(bn8) + 4] = rb1;
    };

    loadG(0, a0, a1, b0, b1);
    stage(0, a0, a1, b0, b1);
    __syncthreads();

    int buf = 0;
    for (int it = 0; it < 24; ++it) {
        if (it < 23) loadG((it + 1) * 16, a0, a1, b0, b1);
#pragma unroll
        for (int kk = 0; kk < 16; ++kk) {
            float av[8], bv[8];
            *(float4*)&av[0] = *(const float4*)&As[buf][kk][ty * 8];
            *(float4*)&av[4] = *(const float4*)&As[buf][kk][ty * 8 + 4];
            *(float4*)&bv[0] = *(const float4*)&Bs[buf][kk][SWZ(tx * 8)];
            *(float4*)&bv[4] = *(const float4*)&Bs[buf][kk][SWZ(tx * 8) + 4];
#pragma unroll
            for (int ii = 0; ii < 8; ++ii)
#pragma unroll
                for (int jj = 0; jj < 8; ++jj)
                    acc[ii][jj] = fmaf(av[ii], bv[jj], acc[ii][jj]);
        }
        if (it < 23) {
            stage(buf ^ 1, a0, a1, b0, b1);
            __syncthreads();
            buf ^= 1;
        }
    }
#pragma unroll
    for (int ii = 0; ii < 8; ++ii) {
        int row = bm + ty * 8 + ii;
        float4 o0 = {acc[ii][0], acc[ii][1], acc[ii][2], acc[ii][3]};
        float4 o1 = {acc[ii][4], acc[ii][5], acc[ii][6], acc[ii][7]};
        float* p = Cmat + (size_t)row * NPAD + bn + tx * 8;
        *(float4*)p = o0;
        *(float4*)(p + 4) = o1;
    }
}

// ---------------- GEMM2: out = P @ Wo, with P given transposed ----------------
// AT = P^T [192][8192] (rows coalesce straight into As[k][m]). BM=128 BN=64
// rm=8 rn=4. grid (3,64)=192 blocks.
__global__ __launch_bounds__(256) void k_gemm2(const float* __restrict__ AT,
                                               const float* __restrict__ B,
                                               float* __restrict__ Cmat) {
    __shared__ float As[2][16][132];
    __shared__ float Bs[2][16][68];
    const int tid = threadIdx.x;
    const int bm = blockIdx.y * 128;
    const int bn = blockIdx.x * 64;
    const int tx = tid & 15, ty = tid >> 4;
    const int ak  = tid >> 4;           // A-load k row 0..15
    const int am8 = (tid & 15) * 8;     // A-load m offset
    const int bkr = tid >> 4;           // B-load k row
    const int bn4 = (tid & 15) * 4;     // B-load col offset

    float acc[8][4] = {};
    float4 a0, a1, b0;

    auto loadG = [&](int k0, float4& ra0, float4& ra1, float4& rb0) {
        const float* pa = AT + (size_t)(k0 + ak) * 8192 + bm + am8;
        ra0 = *(const float4*)pa;
        ra1 = *(const float4*)(pa + 4);
        rb0 = *(const float4*)(B + (size_t)(k0 + bkr) * CC + bn + bn4);
    };
    auto stage = [&](int buf, float4 ra0, float4 ra1, float4 rb0) {
        *(float4*)&As[buf][ak][am8]     = ra0;
        *(float4*)&As[buf][ak][am8 + 4] = ra1;
        *(float4*)&Bs[buf][bkr][bn4]    = rb0;
    };

    loadG(0, a0, a1, b0);
    stage(0, a0, a1, b0);
    __syncthreads();

    int buf = 0;
    for (int it = 0; it < 12; ++it) {
        if (it < 11) loadG((it + 1) * 16, a0, a1, b0);
#pragma unroll
        for (int kk = 0; kk < 16; ++kk) {
            float av[8], bv[4];
            *(float4*)&av[0] = *(const float4*)&As[buf][kk][ty * 8];
            *(float4*)&av[4] = *(const float4*)&As[buf][kk][ty * 8 + 4];
            *(float4*)&bv[0] = *(const float4*)&Bs[buf][kk][tx * 4];
#pragma unroll
            for (int ii = 0; ii < 8; ++ii)
#pragma unroll
                for (int jj = 0; jj < 4; ++jj)
                    acc[ii][jj] = fmaf(av[ii], bv[jj], acc[ii][jj]);
        }
        if (it < 11) {
            stage(buf ^ 1, a0, a1, b0);
            __syncthreads();
            buf ^= 1;
        }
    }
#pragma unroll
    for (int ii = 0; ii < 8; ++ii) {
        int row = bm + ty * 8 + ii;
        float4 o0 = {acc[ii][0], acc[ii][1], acc[ii][2], acc[ii][3]};
        *(float4*)(Cmat + (size_t)row * CC + bn + tx * 4) = o0;
    }
}

// ---------------- fused band_est + ada_peak ----------------
// one block per pixel; band conv + wave0 shuffle-reduce + gather; adds peak
// into the v-section of Z (coalesced RMW).
__global__ __launch_bounds__(192) void k_bandpeak(const float* __restrict__ x,
                                                  const float* __restrict__ cvw,
                                                  const float* __restrict__ cvb,
                                                  const float* __restrict__ bns_v,
                                                  const float* __restrict__ bnb_v,
                                                  const float* __restrict__ chw,
                                                  const float* __restrict__ chb,
                                                  const float* __restrict__ bns_h,
                                                  const float* __restrict__ bnb_h,
                                                  float* __restrict__ Z) {
    int pixg = blockIdx.x;
    int b   = pixg >> 12;
    int pix = pixg & 4095;
    int i = pix >> 6, j = pix & 63;
    int c = threadIdx.x;
    size_t xbase = (size_t)b * TLEN * CC;

    float sv0 = 0.f, sv1 = 0.f, sh0 = 0.f, sh1 = 0.f;
#pragma unroll
    for (int t = 0; t < 7; ++t) {
        int ii = i + t - 3;
        if (ii >= 0 && ii < 64) {
            float xv = x[xbase + (size_t)(ii * 64 + j) * CC + c];
            sv0 = fmaf(xv, cvw[(0 * CC + c) * 7 + t], sv0);
            sv1 = fmaf(xv, cvw[(1 * CC + c) * 7 + t], sv1);
        }
        int jj = j + t - 3;
        if (jj >= 0 && jj < 64) {
            float xh = x[xbase + (size_t)(i * 64 + jj) * CC + c];
            sh0 = fmaf(xh, chw[(0 * CC + c) * 7 + t], sh0);
            sh1 = fmaf(xh, chw[(1 * CC + c) * 7 + t], sh1);
        }
    }
    __shared__ float red[4][CC];
    __shared__ float gsh[4];
    red[0][c] = sv0; red[1][c] = sv1; red[2][c] = sh0; red[3][c] = sh1;
    __syncthreads();
    if (c < 64) {
#pragma unroll
        for (int r = 0; r < 4; ++r) {
            float v = red[r][c] + red[r][c + 64] + red[r][c + 128];
            v += __shfl_xor(v, 32);
            v += __shfl_xor(v, 16);
            v += __shfl_xor(v, 8);
            v += __shfl_xor(v, 4);
            v += __shfl_xor(v, 2);
            v += __shfl_xor(v, 1);
            if (c == 0) {
                const float inv = 0.9999950000374997f;    // 1/sqrt(1+1e-5)
                float bias, sc, sh;
                if (r < 2) { bias = cvb[r];     sc = bns_v[r];     sh = bnb_v[r]; }
                else       { bias = chb[r - 2]; sc = bns_h[r - 2]; sh = bnb_h[r - 2]; }
                float g = (v + bias) * (sc * inv) + sh;
                gsh[r] = 2.0f / (1.0f + expf(-g));        // sigmoid * (GB_MAX-1)
            }
        }
    }
    __syncthreads();

    __shared__ int   l_lt[16], l_rb[16];
    __shared__ float l_glt[16], l_grb[16];
    if (c < 16) {
        int n = c, blk = n >> 2;
        float g0 = gsh[0], g1 = gsh[1], g2 = gsh[2], g3 = gsh[3];
        float mx = (blk == 0) ? -g0 : (blk == 2) ? g1 : 0.0f;
        float my = (blk == 1) ?  g3 : (blk == 3) ? -g2 : 0.0f;
        float px = (float)(i + PADC) + PRF_X[n] + mx;
        float py = (float)(j + PADC) + PRF_Y[n] + my;
        float flx = floorf(px), fly = floorf(py);
        float qltx = fminf(fmaxf(flx, 0.f), 67.f);
        float qlty = fminf(fmaxf(fly, 0.f), 67.f);
        float qrbx = fminf(fmaxf(flx + 1.f, 0.f), 67.f);
        float qrby = fminf(fmaxf(fly + 1.f, 0.f), 67.f);
        float pxc = fminf(fmaxf(px, 0.f), 67.f);
        float pyc = fminf(fmaxf(py, 0.f), 67.f);
        float glt = (1.f + (qltx - pxc)) * (1.f + (qlty - pyc));
        float grb = (1.f - (qrbx - pxc)) * (1.f - (qrby - pyc));
        int sltx = min(max((int)qltx - PADC, 0), 63);
        int slty = min(max((int)qlty - PADC, 0), 63);
        int srbx = min(max((int)qrbx - PADC, 0), 63);
        int srby = min(max((int)qrby - PADC, 0), 63);
        l_lt[n] = sltx * 64 + slty;
        l_rb[n] = srbx * 64 + srby;
        l_glt[n] = glt;
        l_grb[n] = grb;
    }
    __syncthreads();

    float acc = 0.f;
#pragma unroll
    for (int n = 0; n < 16; ++n) {
        acc = fmaf(l_glt[n], x[xbase + (size_t)l_lt[n] * CC + c], acc);
        acc = fmaf(l_grb[n], x[xbase + (size_t)l_rb[n] * CC + c], acc);
    }
    float peak = x[xbase + (size_t)pix * CC + c] - acc * 0.0625f;
    size_t zi = ((size_t)b * TLEN + pix) * NPAD + CC + c;   // v-section
    Z[zi] += peak;
}

// ---------------- bi_wkv: chunked associative scan, all state in registers ----
// one block per (b,c); 256 threads x 16-element chunks. Reads Z strided
// (L2/L3-served), applies sigmoid(r) inline, writes P^T [192][8192] coalesced.
__global__ __launch_bounds__(256) void k_wkv2(const float* __restrict__ Z,
                                              float* __restrict__ PT,
                                              const float* __restrict__ sd,
                                              const float* __restrict__ sf) {
    const int NTH = 256, CH = 16;
    int c = blockIdx.x % CC;
    int b = blockIdx.x / CC;
    const float w = sd[c] * (1.0f / 4096.0f);
    const float u = sf[c] * (1.0f / 4096.0f);

    __shared__ float s_m[NTH], s_a[NTH], s_b[NTH], s_L[NTH];

    int tid = threadIdx.x;
    int s = tid * CH;
    size_t rowbase = (size_t)b * TLEN;

    float kr[CH], vr[CH], rr[CH];
#pragma unroll
    for (int jj = 0; jj < CH; ++jj) {
        const float* p = Z + (rowbase + s + jj) * NPAD + c;
        kr[jj] = p[0];
        vr[jj] = p[CC];
        rr[jj] = p[2 * CC];
    }

    // ---- forward local chunk summary
    float m = -1e38f, a = 0.f, bb = 0.f;
#pragma unroll
    for (int jj = 0; jj < CH; ++jj) {
        float kt = kr[jj], vt = vr[jj];
        float m2 = fmaxf(m - w, kt);
        float e1 = expf(m - w - m2);
        float e2 = expf(kt - m2);
        a = e1 * a + e2;
        bb = e1 * bb + e2 * vt;
        m = m2;
    }
    // ---- inclusive prefix scan of summaries
    s_m[tid] = m; s_a[tid] = a; s_b[tid] = bb; s_L[tid] = (float)CH;
    float L = (float)CH;
    for (int d = 1; d < NTH; d <<= 1) {
        __syncthreads();
        float pm = 0, pa = 0, pb = 0, pL = 0;
        bool has = (tid >= d);
        if (has) { pm = s_m[tid - d]; pa = s_a[tid - d]; pb = s_b[tid - d]; pL = s_L[tid - d]; }
        __syncthreads();
        if (has) {
            float pdec = pm - L * w;
            float m2 = fmaxf(pdec, m);
            float e1 = expf(pdec - m2);
            float e2 = expf(m - m2);
            a  = e1 * pa + e2 * a;
            bb = e1 * pb + e2 * bb;
            m = m2; L += pL;
            s_m[tid] = m; s_a[tid] = a; s_b[tid] = bb; s_L[tid] = L;
        }
    }
    __syncthreads();
    float fm = -1e38f, fa = 0.f, fb = 0.f;
    if (tid > 0) { fm = s_m[tid - 1]; fa = s_a[tid - 1]; fb = s_b[tid - 1]; }
    __syncthreads();

    // ---- backward local chunk summary
    m = -1e38f; a = 0.f; bb = 0.f;
#pragma unroll
    for (int jj = CH - 1; jj >= 0; --jj) {
        float kt = kr[jj], vt = vr[jj];
        float m2 = fmaxf(m - w, kt);
        float e1 = expf(m - w - m2);
        float e2 = expf(kt - m2);
        a = e1 * a + e2;
        bb = e1 * bb + e2 * vt;
        m = m2;
    }
    // ---- inclusive suffix scan
    s_m[tid] = m; s_a[tid] = a; s_b[tid] = bb; s_L[tid] = (float)CH;
    L = (float)CH;
    for (int d = 1; d < NTH; d <<= 1) {
        __syncthreads();
        float pm = 0, pa = 0, pb = 0, pL = 0;
        bool has = (tid + d) < NTH;
        if (has) { pm = s_m[tid + d]; pa = s_a[tid + d]; pb = s_b[tid + d]; pL = s_L[tid + d]; }
        __syncthreads();
        if (has) {
            float pdec = pm - L * w;
            float m2 = fmaxf(m, pdec);
            float e1 = expf(m - m2);
            float e2 = expf(pdec - m2);
            a  = e1 * a + e2 * pa;
            bb = e1 * bb + e2 * pb;
            m = m2; L += pL;
            s_m[tid] = m; s_a[tid] = a; s_b[tid] = bb; s_L[tid] = L;
        }
    }
    __syncthreads();
    float bm = -1e38f, ba = 0.f, bbv = 0.f;
    if (tid < NTH - 1) { bm = s_m[tid + 1]; ba = s_a[tid + 1]; bbv = s_b[tid + 1]; }

    // ---- backward re-scan: per-element backward states into registers
    float em[CH], ea[CH], eb[CH];
    m = bm; a = ba; bb = bbv;
#pragma unroll
    for (int jj = CH - 1; jj >= 0; --jj) {
        em[jj] = m; ea[jj] = a; eb[jj] = bb;
        float kt = kr[jj], vt = vr[jj];
        float m2 = fmaxf(m - w, kt);
        float e1 = expf(m - w - m2);
        float e2 = expf(kt - m2);
        a = e1 * a + e2;
        bb = e1 * bb + e2 * vt;
        m = m2;
    }

    // ---- forward re-scan + combine + output P^T = sigmoid(r) * y
    m = fm; a = fa; bb = fb;
#pragma unroll
    for (int jj = 0; jj < CH; ++jj) {
        float kt = kr[jj], vt = vr[jj];
        float ms = u + kt;
        float M = fmaxf(fmaxf(m, em[jj]), ms);
        float ef  = expf(m - M);
        float ebk = expf(em[jj] - M);
        float es  = expf(ms - M);
        float num = ef * bb + ebk * eb[jj] + es * vt;
        float den = ef * a + ebk * ea[jj] + es;
        float y = num / den;
        float sr = 1.0f / (1.0f + expf(-rr[jj]));
        PT[(size_t)c * (BATCH * TLEN) + rowbase + s + jj] = sr * y;
        float m2 = fmaxf(m - w, kt);
        float e1 = expf(m - w - m2);
        float e2 = expf(kt - m2);
        a = e1 * a + e2;
        bb = e1 * bb + e2 * vt;
        m = m2;
    }
}

extern "C" void kernel_launch(void* const* d_in, const int* in_sizes, int n_in,
                              void* d_out, int out_size, void* d_ws, size_t ws_size,
                              hipStream_t stream) {
    const float* x     = (const float*)d_in[0];
    const float* mix_k = (const float*)d_in[3];
    const float* mix_v = (const float*)d_in[4];
    const float* mix_r = (const float*)d_in[5];
    const float* Wk    = (const float*)d_in[6];
    const float* Wv    = (const float*)d_in[7];
    const float* Wr    = (const float*)d_in[8];
    const float* Wo    = (const float*)d_in[9];
    const float* sd    = (const float*)d_in[10];
    const float* sf    = (const float*)d_in[11];
    const float* cvw   = (const float*)d_in[12];
    const float* cvb   = (const float*)d_in[13];
    const float* bns_v = (const float*)d_in[14];
    const float* bnb_v = (const float*)d_in[15];
    const float* chw   = (const float*)d_in[16];
    const float* chb   = (const float*)d_in[17];
    const float* bns_h = (const float*)d_in[18];
    const float* bnb_h = (const float*)d_in[19];
    float* out = (float*)d_out;
    float* ws  = (float*)d_ws;

    // workspace layout (floats):
    float* XX   = ws;                 // 1,572,864   (also reused as PT after GEMM1)
    float* Z    = ws + 1572864;       // 5,242,880   (8192 x 640: k|v|r|pad)
    float* Wcat = ws + 6815744;       //   245,760   (384 x 640)
    float* PT   = XX;                 // PT = P^T [192][8192], reuses XX region

    k_build_xx<<<6144, 256, 0, stream>>>(x, XX);
    k_build_wcat<<<960, 256, 0, stream>>>(Wk, Wv, Wr, mix_k, mix_v, mix_r, Wcat);
    k_gemm1<<<dim3(5, 64), 256, 0, stream>>>(x, XX, Wcat, Z);
    k_bandpeak<<<8192, 192, 0, stream>>>(x, cvw, cvb, bns_v, bnb_v, chw, chb, bns_h, bnb_h, Z);
    k_wkv2<<<384, 256, 0, stream>>>(Z, PT, sd, sf);
    k_gemm2<<<dim3(3, 64), 256, 0, stream>>>(PT, Wo, out);
}

// Round 6
// 238.367 us; speedup vs baseline: 1.2921x; 1.2921x over previous
//
#include <hip/hip_runtime.h>
#include <hip/hip_bf16.h>

// Problem constants (fixed by setup_inputs): B=2, H=W=64, T=4096, C=192
#define BATCH 2
#define TLEN 4096
#define CC 192
#define NTOT 576          // 3*C output cols of GEMM1 (k|v|r)
#define PADC 2

__device__ __constant__ float PRF_X[16] = {-2,-2,-2,-2, -2,-1,0,1, 2,2,2,2, -1,0,1,2};
__device__ __constant__ float PRF_Y[16] = {-2,-1,0,1, 2,2,2,2, -1,0,1,2, -2,-2,-2,-2};

// As swizzle: +4 floats every 32 (breaks power-of-2 stride conflicts).
// Any 8-aligned 8-float run keeps a constant offset (boundaries at mult-of-32).
#define ASWZ(n) ((n) + (((n) >> 5) << 2))

// ---------------- build concatenated, mix-scaled weights ----------------
// Wcat (384 x 576): rows 0..191 = mix[c]*W[c,:], rows 192..383 = (1-mix[c])*W[c,:]
__global__ __launch_bounds__(256) void k_build_wcat(const float* __restrict__ Wk,
                                                    const float* __restrict__ Wv,
                                                    const float* __restrict__ Wr,
                                                    const float* __restrict__ mk,
                                                    const float* __restrict__ mv,
                                                    const float* __restrict__ mr,
                                                    float* __restrict__ Wcat) {
    int idx = blockIdx.x * 256 + threadIdx.x;
    if (idx >= 384 * NTOT) return;
    int r   = idx / NTOT;
    int col = idx - r * NTOT;
    int cb = col / CC;
    int cc = col - cb * CC;
    const float* W   = (cb == 0) ? Wk : (cb == 1) ? Wv : Wr;
    const float* mix = (cb == 0) ? mk : (cb == 1) ? mv : mr;
    float v;
    if (r < CC) v = mix[r] * W[r * CC + cc];
    else        v = (1.0f - mix[r - CC]) * W[(r - CC) * CC + cc];
    Wcat[idx] = v;
}

// ---------------- GEMM1: [x | qshift(x)] @ Wcat ----------------
// M=8192 N=576 K=384. BM=128 BN=64 BK=16, 256 threads, 8x4 micro-tile.
// q_shift folded into the A-load for k>=192. Epilogue: k,r sections written
// TRANSPOSED ([C][8192] planes); v section written pixel-major (for bandpeak RMW).
__global__ __launch_bounds__(256) void k_gemm1(const float* __restrict__ x,
                                               const float* __restrict__ Wcat,
                                               float* __restrict__ ZTk,
                                               float* __restrict__ Zv,
                                               float* __restrict__ ZTr) {
    __shared__ float As[2][16][140];
    __shared__ float Bs[2][16][68];
    const int tid = threadIdx.x;
    const int bm = blockIdx.y * 128;
    const int bn = blockIdx.x * 64;
    const int tx = tid & 15, ty = tid >> 4;
    const int ar  = tid >> 1;           // A-load row 0..127
    const int akh = (tid & 1) * 8;      // A-load k offset
    const int bk  = tid >> 4;           // B-load k row 0..15
    const int bn4 = (tid & 15) * 4;     // B-load col offset

    const int row = bm + ar;            // global row 0..8191
    const int t   = row & (TLEN - 1);
    const int ri  = t >> 6, rj = t & 63;

    float acc[8][4] = {};
    float4 a0, a1, b0;

    auto loadG = [&](int k0, float4& ra0, float4& ra1, float4& rb0) {
        if (k0 < CC) {
            const float* pa = x + (size_t)row * CC + k0 + akh;
            ra0 = *(const float4*)pa;
            ra1 = *(const float4*)(pa + 4);
        } else {
            int c = k0 - CC + akh;          // 0..184, 8-run stays in one group
            int g = c / 48;
            int dr; bool ok;
            if      (g == 0) { dr = -1;  ok = (rj > 0);  }
            else if (g == 1) { dr =  1;  ok = (rj < 63); }
            else if (g == 2) { dr = -64; ok = (ri > 0);  }
            else             { dr =  64; ok = (ri < 63); }
            if (ok) {
                const float* pa = x + (size_t)(row + dr) * CC + c;
                ra0 = *(const float4*)pa;
                ra1 = *(const float4*)(pa + 4);
            } else {
                ra0 = make_float4(0.f, 0.f, 0.f, 0.f);
                ra1 = make_float4(0.f, 0.f, 0.f, 0.f);
            }
        }
        rb0 = *(const float4*)(Wcat + (size_t)(k0 + bk) * NTOT + bn + bn4);
    };
    auto stage = [&](int buf, float4 ra0, float4 ra1, float4 rb0) {
        int sa = ASWZ(ar);
        As[buf][akh + 0][sa] = ra0.x; As[buf][akh + 1][sa] = ra0.y;
        As[buf][akh + 2][sa] = ra0.z; As[buf][akh + 3][sa] = ra0.w;
        As[buf][akh + 4][sa] = ra1.x; As[buf][akh + 5][sa] = ra1.y;
        As[buf][akh + 6][sa] = ra1.z; As[buf][akh + 7][sa] = ra1.w;
        *(float4*)&Bs[buf][bk][bn4] = rb0;
    };

    loadG(0, a0, a1, b0);
    stage(0, a0, a1, b0);
    __syncthreads();

    const int abase = ASWZ(ty * 8);
    int buf = 0;
    for (int it = 0; it < 24; ++it) {
        if (it < 23) loadG((it + 1) * 16, a0, a1, b0);
#pragma unroll
        for (int kk = 0; kk < 16; ++kk) {
            float av[8], bv[4];
            *(float4*)&av[0] = *(const float4*)&As[buf][kk][abase];
            *(float4*)&av[4] = *(const float4*)&As[buf][kk][abase + 4];
            *(float4*)&bv[0] = *(const float4*)&Bs[buf][kk][tx * 4];
#pragma unroll
            for (int ii = 0; ii < 8; ++ii)
#pragma unroll
                for (int jj = 0; jj < 4; ++jj)
                    acc[ii][jj] = fmaf(av[ii], bv[jj], acc[ii][jj]);
        }
        if (it < 23) {
            stage(buf ^ 1, a0, a1, b0);
            __syncthreads();
            buf ^= 1;
        }
    }

    const int sec = bn / CC;            // 0=k 1=v 2=r (64-wide tile fits one section)
    const int col0 = bn - sec * CC + tx * 4;
    if (sec == 1) {
        // v: pixel-major [8192][192]
#pragma unroll
        for (int ii = 0; ii < 8; ++ii) {
            int r2 = bm + ty * 8 + ii;
            float4 o = {acc[ii][0], acc[ii][1], acc[ii][2], acc[ii][3]};
            *(float4*)(Zv + (size_t)r2 * CC + col0) = o;
        }
    } else {
        float* D = (sec == 0) ? ZTk : ZTr;
        int row0 = bm + ty * 8;
#pragma unroll
        for (int jj = 0; jj < 4; ++jj) {
            float4 o0 = {acc[0][jj], acc[1][jj], acc[2][jj], acc[3][jj]};
            float4 o1 = {acc[4][jj], acc[5][jj], acc[6][jj], acc[7][jj]};
            float* p = D + (size_t)(col0 + jj) * 8192 + row0;
            *(float4*)p = o0;
            *(float4*)(p + 4) = o1;
        }
    }
}

// ---------------- GEMM2: out = P @ Wo, P given transposed ----------------
__global__ __launch_bounds__(256) void k_gemm2(const float* __restrict__ AT,
                                               const float* __restrict__ B,
                                               float* __restrict__ Cmat) {
    __shared__ float As[2][16][132];
    __shared__ float Bs[2][16][68];
    const int tid = threadIdx.x;
    const int bm = blockIdx.y * 128;
    const int bn = blockIdx.x * 64;
    const int tx = tid & 15, ty = tid >> 4;
    const int ak  = tid >> 4;
    const int am8 = (tid & 15) * 8;
    const int bkr = tid >> 4;
    const int bn4 = (tid & 15) * 4;

    float acc[8][4] = {};
    float4 a0, a1, b0;

    auto loadG = [&](int k0, float4& ra0, float4& ra1, float4& rb0) {
        const float* pa = AT + (size_t)(k0 + ak) * 8192 + bm + am8;
        ra0 = *(const float4*)pa;
        ra1 = *(const float4*)(pa + 4);
        rb0 = *(const float4*)(B + (size_t)(k0 + bkr) * CC + bn + bn4);
    };
    auto stage = [&](int buf, float4 ra0, float4 ra1, float4 rb0) {
        *(float4*)&As[buf][ak][am8]     = ra0;
        *(float4*)&As[buf][ak][am8 + 4] = ra1;
        *(float4*)&Bs[buf][bkr][bn4]    = rb0;
    };

    loadG(0, a0, a1, b0);
    stage(0, a0, a1, b0);
    __syncthreads();

    int buf = 0;
    for (int it = 0; it < 12; ++it) {
        if (it < 11) loadG((it + 1) * 16, a0, a1, b0);
#pragma unroll
        for (int kk = 0; kk < 16; ++kk) {
            float av[8], bv[4];
            *(float4*)&av[0] = *(const float4*)&As[buf][kk][ty * 8];
            *(float4*)&av[4] = *(const float4*)&As[buf][kk][ty * 8 + 4];
            *(float4*)&bv[0] = *(const float4*)&Bs[buf][kk][tx * 4];
#pragma unroll
            for (int ii = 0; ii < 8; ++ii)
#pragma unroll
                for (int jj = 0; jj < 4; ++jj)
                    acc[ii][jj] = fmaf(av[ii], bv[jj], acc[ii][jj]);
        }
        if (it < 11) {
            stage(buf ^ 1, a0, a1, b0);
            __syncthreads();
            buf ^= 1;
        }
    }
#pragma unroll
    for (int ii = 0; ii < 8; ++ii) {
        int row = bm + ty * 8 + ii;
        float4 o0 = {acc[ii][0], acc[ii][1], acc[ii][2], acc[ii][3]};
        *(float4*)(Cmat + (size_t)row * CC + bn + tx * 4) = o0;
    }
}

// ---------------- fused band_est + ada_peak (RMW into pixel-major Zv) -------
__global__ __launch_bounds__(192) void k_bandpeak(const float* __restrict__ x,
                                                  const float* __restrict__ cvw,
                                                  const float* __restrict__ cvb,
                                                  const float* __restrict__ bns_v,
                                                  const float* __restrict__ bnb_v,
                                                  const float* __restrict__ chw,
                                                  const float* __restrict__ chb,
                                                  const float* __restrict__ bns_h,
                                                  const float* __restrict__ bnb_h,
                                                  float* __restrict__ Zv) {
    int pixg = blockIdx.x;
    int b   = pixg >> 12;
    int pix = pixg & 4095;
    int i = pix >> 6, j = pix & 63;
    int c = threadIdx.x;
    size_t xbase = (size_t)b * TLEN * CC;

    float sv0 = 0.f, sv1 = 0.f, sh0 = 0.f, sh1 = 0.f;
#pragma unroll
    for (int t = 0; t < 7; ++t) {
        int ii = i + t - 3;
        if (ii >= 0 && ii < 64) {
            float xv = x[xbase + (size_t)(ii * 64 + j) * CC + c];
            sv0 = fmaf(xv, cvw[(0 * CC + c) * 7 + t], sv0);
            sv1 = fmaf(xv, cvw[(1 * CC + c) * 7 + t], sv1);
        }
        int jj = j + t - 3;
        if (jj >= 0 && jj < 64) {
            float xh = x[xbase + (size_t)(i * 64 + jj) * CC + c];
            sh0 = fmaf(xh, chw[(0 * CC + c) * 7 + t], sh0);
            sh1 = fmaf(xh, chw[(1 * CC + c) * 7 + t], sh1);
        }
    }
    __shared__ float red[4][CC];
    __shared__ float gsh[4];
    red[0][c] = sv0; red[1][c] = sv1; red[2][c] = sh0; red[3][c] = sh1;
    __syncthreads();
    if (c < 64) {
#pragma unroll
        for (int r = 0; r < 4; ++r) {
            float v = red[r][c] + red[r][c + 64] + red[r][c + 128];
            v += __shfl_xor(v, 32);
            v += __shfl_xor(v, 16);
            v += __shfl_xor(v, 8);
            v += __shfl_xor(v, 4);
            v += __shfl_xor(v, 2);
            v += __shfl_xor(v, 1);
            if (c == 0) {
                const float inv = 0.9999950000374997f;    // 1/sqrt(1+1e-5)
                float bias, sc, sh;
                if (r < 2) { bias = cvb[r];     sc = bns_v[r];     sh = bnb_v[r]; }
                else       { bias = chb[r - 2]; sc = bns_h[r - 2]; sh = bnb_h[r - 2]; }
                float g = (v + bias) * (sc * inv) + sh;
                gsh[r] = 2.0f / (1.0f + expf(-g));        // sigmoid * (GB_MAX-1)
            }
        }
    }
    __syncthreads();

    __shared__ int   l_lt[16], l_rb[16];
    __shared__ float l_glt[16], l_grb[16];
    if (c < 16) {
        int n = c, blk = n >> 2;
        float mx = (blk == 0) ? -gsh[0] : (blk == 2) ? gsh[1] : 0.0f;
        float my = (blk == 1) ?  gsh[3] : (blk == 3) ? -gsh[2] : 0.0f;
        float px = (float)(i + PADC) + PRF_X[n] + mx;
        float py = (float)(j + PADC) + PRF_Y[n] + my;
        float flx = floorf(px), fly = floorf(py);
        float qltx = fminf(fmaxf(flx, 0.f), 67.f);
        float qlty = fminf(fmaxf(fly, 0.f), 67.f);
        float qrbx = fminf(fmaxf(flx + 1.f, 0.f), 67.f);
        float qrby = fminf(fmaxf(fly + 1.f, 0.f), 67.f);
        float pxc = fminf(fmaxf(px, 0.f), 67.f);
        float pyc = fminf(fmaxf(py, 0.f), 67.f);
        float glt = (1.f + (qltx - pxc)) * (1.f + (qlty - pyc));
        float grb = (1.f - (qrbx - pxc)) * (1.f - (qrby - pyc));
        int sltx = min(max((int)qltx - PADC, 0), 63);
        int slty = min(max((int)qlty - PADC, 0), 63);
        int srbx = min(max((int)qrbx - PADC, 0), 63);
        int srby = min(max((int)qrby - PADC, 0), 63);
        l_lt[n] = sltx * 64 + slty;
        l_rb[n] = srbx * 64 + srby;
        l_glt[n] = glt;
        l_grb[n] = grb;
    }
    __syncthreads();

    float acc = 0.f;
#pragma unroll
    for (int n = 0; n < 16; ++n) {
        acc = fmaf(l_glt[n], x[xbase + (size_t)l_lt[n] * CC + c], acc);
        acc = fmaf(l_grb[n], x[xbase + (size_t)l_rb[n] * CC + c], acc);
    }
    float peak = x[xbase + (size_t)pix * CC + c] - acc * 0.0625f;
    Zv[((size_t)b * TLEN + pix) * CC + c] += peak;
}

// ---------------- transpose v: Zv[8192][192] -> ZTv[192][8192] ----------------
__global__ __launch_bounds__(256) void k_transv(const float* __restrict__ Zv,
                                                float* __restrict__ ZTv) {
    __shared__ float tile[64][65];
    int tid = threadIdx.x;
    int rb = (blockIdx.x & 127) * 64;     // rows over 8192
    int cb = (blockIdx.x >> 7) * 64;      // cols over 192 (3 tiles)
    int tr  = tid >> 4;                   // 0..15
    int tc4 = (tid & 15) * 4;             // 0..60
#pragma unroll
    for (int q = 0; q < 4; ++q) {
        int r = tr + q * 16;
        float4 v = *(const float4*)(Zv + (size_t)(rb + r) * CC + cb + tc4);
        *(float4*)&tile[r][tc4] = v;
    }
    __syncthreads();
#pragma unroll
    for (int q = 0; q < 4; ++q) {
        int ccol = tr + q * 16;
        float4 o = {tile[tc4 + 0][ccol], tile[tc4 + 1][ccol],
                    tile[tc4 + 2][ccol], tile[tc4 + 3][ccol]};
        *(float4*)(ZTv + (size_t)(cb + ccol) * 8192 + rb + tc4) = o;
    }
}

// ---------------- bi_wkv: chunked associative scan, coalesced ZT loads -------
__global__ __launch_bounds__(256) void k_wkv2(const float* __restrict__ ZT,
                                              float* __restrict__ PT,
                                              const float* __restrict__ sd,
                                              const float* __restrict__ sf) {
    const int NTH = 256, CH = 16;
    int c = blockIdx.x % CC;
    int b = blockIdx.x / CC;
    const float w = sd[c] * (1.0f / 4096.0f);
    const float u = sf[c] * (1.0f / 4096.0f);

    __shared__ float s_m[NTH], s_a[NTH], s_b[NTH], s_L[NTH];

    int tid = threadIdx.x;
    int s = tid * CH;
    size_t rowbase = (size_t)b * TLEN;

    float kr[CH], vr[CH], rr[CH];
    {
        const float* pk = ZT + (size_t)c * 8192 + rowbase + s;
        const float* pv = ZT + (size_t)(CC + c) * 8192 + rowbase + s;
        const float* pr = ZT + (size_t)(2 * CC + c) * 8192 + rowbase + s;
#pragma unroll
        for (int q = 0; q < 4; ++q) {
            *(float4*)&kr[q * 4] = *(const float4*)(pk + q * 4);
            *(float4*)&vr[q * 4] = *(const float4*)(pv + q * 4);
            *(float4*)&rr[q * 4] = *(const float4*)(pr + q * 4);
        }
    }

    // ---- forward local chunk summary
    float m = -1e38f, a = 0.f, bb = 0.f;
#pragma unroll
    for (int jj = 0; jj < CH; ++jj) {
        float kt = kr[jj], vt = vr[jj];
        float m2 = fmaxf(m - w, kt);
        float e1 = expf(m - w - m2);
        float e2 = expf(kt - m2);
        a = e1 * a + e2;
        bb = e1 * bb + e2 * vt;
        m = m2;
    }
    // ---- inclusive prefix scan of summaries
    s_m[tid] = m; s_a[tid] = a; s_b[tid] = bb; s_L[tid] = (float)CH;
    float L = (float)CH;
    for (int d = 1; d < NTH; d <<= 1) {
        __syncthreads();
        float pm = 0, pa = 0, pb = 0, pL = 0;
        bool has = (tid >= d);
        if (has) { pm = s_m[tid - d]; pa = s_a[tid - d]; pb = s_b[tid - d]; pL = s_L[tid - d]; }
        __syncthreads();
        if (has) {
            float pdec = pm - L * w;
            float m2 = fmaxf(pdec, m);
            float e1 = expf(pdec - m2);
            float e2 = expf(m - m2);
            a  = e1 * pa + e2 * a;
            bb = e1 * pb + e2 * bb;
            m = m2; L += pL;
            s_m[tid] = m; s_a[tid] = a; s_b[tid] = bb; s_L[tid] = L;
        }
    }
    __syncthreads();
    float fm = -1e38f, fa = 0.f, fb = 0.f;
    if (tid > 0) { fm = s_m[tid - 1]; fa = s_a[tid - 1]; fb = s_b[tid - 1]; }
    __syncthreads();

    // ---- backward local chunk summary
    m = -1e38f; a = 0.f; bb = 0.f;
#pragma unroll
    for (int jj = CH - 1; jj >= 0; --jj) {
        float kt = kr[jj], vt = vr[jj];
        float m2 = fmaxf(m - w, kt);
        float e1 = expf(m - w - m2);
        float e2 = expf(kt - m2);
        a = e1 * a + e2;
        bb = e1 * bb + e2 * vt;
        m = m2;
    }
    // ---- inclusive suffix scan
    s_m[tid] = m; s_a[tid] = a; s_b[tid] = bb; s_L[tid] = (float)CH;
    L = (float)CH;
    for (int d = 1; d < NTH; d <<= 1) {
        __syncthreads();
        float pm = 0, pa = 0, pb = 0, pL = 0;
        bool has = (tid + d) < NTH;
        if (has) { pm = s_m[tid + d]; pa = s_a[tid + d]; pb = s_b[tid + d]; pL = s_L[tid + d]; }
        __syncthreads();
        if (has) {
            float pdec = pm - L * w;
            float m2 = fmaxf(m, pdec);
            float e1 = expf(m - m2);
            float e2 = expf(pdec - m2);
            a  = e1 * a + e2 * pa;
            bb = e1 * bb + e2 * pb;
            m = m2; L += pL;
            s_m[tid] = m; s_a[tid] = a; s_b[tid] = bb; s_L[tid] = L;
        }
    }
    __syncthreads();
    float bm = -1e38f, ba = 0.f, bbv = 0.f;
    if (tid < NTH - 1) { bm = s_m[tid + 1]; ba = s_a[tid + 1]; bbv = s_b[tid + 1]; }

    // ---- backward re-scan: per-element backward states into registers
    float em[CH], ea[CH], eb[CH];
    m = bm; a = ba; bb = bbv;
#pragma unroll
    for (int jj = CH - 1; jj >= 0; --jj) {
        em[jj] = m; ea[jj] = a; eb[jj] = bb;
        float kt = kr[jj], vt = vr[jj];
        float m2 = fmaxf(m - w, kt);
        float e1 = expf(m - w - m2);
        float e2 = expf(kt - m2);
        a = e1 * a + e2;
        bb = e1 * bb + e2 * vt;
        m = m2;
    }

    // ---- forward re-scan + combine + output P^T = sigmoid(r) * y
    m = fm; a = fa; bb = fb;
#pragma unroll
    for (int jj = 0; jj < CH; ++jj) {
        float kt = kr[jj], vt = vr[jj];
        float ms = u + kt;
        float M = fmaxf(fmaxf(m, em[jj]), ms);
        float ef  = expf(m - M);
        float ebk = expf(em[jj] - M);
        float es  = expf(ms - M);
        float num = ef * bb + ebk * eb[jj] + es * vt;
        float den = ef * a + ebk * ea[jj] + es;
        float y = num / den;
        float sr = 1.0f / (1.0f + expf(-rr[jj]));
        PT[(size_t)c * 8192 + rowbase + s + jj] = sr * y;
        float m2 = fmaxf(m - w, kt);
        float e1 = expf(m - w - m2);
        float e2 = expf(kt - m2);
        a = e1 * a + e2;
        bb = e1 * bb + e2 * vt;
        m = m2;
    }
}

extern "C" void kernel_launch(void* const* d_in, const int* in_sizes, int n_in,
                              void* d_out, int out_size, void* d_ws, size_t ws_size,
                              hipStream_t stream) {
    const float* x     = (const float*)d_in[0];
    const float* mix_k = (const float*)d_in[3];
    const float* mix_v = (const float*)d_in[4];
    const float* mix_r = (const float*)d_in[5];
    const float* Wk    = (const float*)d_in[6];
    const float* Wv    = (const float*)d_in[7];
    const float* Wr    = (const float*)d_in[8];
    const float* Wo    = (const float*)d_in[9];
    const float* sd    = (const float*)d_in[10];
    const float* sf    = (const float*)d_in[11];
    const float* cvw   = (const float*)d_in[12];
    const float* cvb   = (const float*)d_in[13];
    const float* bns_v = (const float*)d_in[14];
    const float* bnb_v = (const float*)d_in[15];
    const float* chw   = (const float*)d_in[16];
    const float* chb   = (const float*)d_in[17];
    const float* bns_h = (const float*)d_in[18];
    const float* bnb_h = (const float*)d_in[19];
    float* out = (float*)d_out;
    float* ws  = (float*)d_ws;

    // workspace layout (floats), total 6,512,640 fl = 26.1 MB:
    float* Zv   = ws;                  // 1,572,864  [8192][192] pixel-major v
    float* ZT   = ws + 1572864;        // 4,718,592  [3][192][8192] k|v|r planes
    float* Wcat = ws + 6291456;        //   221,184  [384][576]
    float* ZTk  = ZT;
    float* ZTv  = ZT + 1572864;
    float* ZTr  = ZT + 3145728;
    float* PT   = Zv;                  // reuse: Zv dead after k_transv

    k_build_wcat<<<864, 256, 0, stream>>>(Wk, Wv, Wr, mix_k, mix_v, mix_r, Wcat);
    k_gemm1<<<dim3(9, 64), 256, 0, stream>>>(x, Wcat, ZTk, Zv, ZTr);
    k_bandpeak<<<8192, 192, 0, stream>>>(x, cvw, cvb, bns_v, bnb_v, chw, chb, bns_h, bnb_h, Zv);
    k_transv<<<384, 256, 0, stream>>>(Zv, ZTv);
    k_wkv2<<<384, 256, 0, stream>>>(ZT, PT, sd, sf);
    k_gemm2<<<dim3(3, 64), 256, 0, stream>>>(PT, Wo, out);
}